// Round 1
// baseline (4036.744 us; speedup 1.0000x reference)
//
#include <hip/hip_runtime.h>
#include <float.h>

#define BM 64
#define BN 256
#define BK 32
#define D 512
#define NCHUNKS 24

// Insert (v,id) into ascending sorted 5-list held in registers.
__device__ __forceinline__ void insert5(float* bs, int* bi, float v, int id) {
    if (v < bs[4]) {
        bs[4] = v; bi[4] = id;
#pragma unroll
        for (int r = 4; r >= 1; --r) {
            if (bs[r] < bs[r - 1]) {
                float tf = bs[r]; bs[r] = bs[r - 1]; bs[r - 1] = tf;
                int ti = bi[r]; bi[r] = bi[r - 1]; bi[r - 1] = ti;
            }
        }
    }
}

// ||x_n||^2 for every fitted row. One wave per row, 4 waves per block.
__global__ void xsq_kernel(const float* __restrict__ X, float* __restrict__ xsq, int N) {
    int row = blockIdx.x * 4 + (threadIdx.x >> 6);
    int lane = threadIdx.x & 63;
    if (row >= N) return;
    const float4* p = (const float4*)(X + (size_t)row * D);
    float4 a = p[lane];
    float4 b = p[lane + 64];
    float s = a.x * a.x + a.y * a.y + a.z * a.z + a.w * a.w
            + b.x * b.x + b.y * b.y + b.z * b.z + b.w * b.w;
#pragma unroll
    for (int off = 32; off > 0; off >>= 1) s += __shfl_down(s, off, 64);
    if (lane == 0) xsq[row] = s;
}

// Fused distance-GEMM + per-(query,chunk) top-5.
// score(n) = xsq[n] - 2*dot(q, x_n)  (q_sq omitted: constant per query).
__global__ __launch_bounds__(256, 2) void score_kernel(
    const float* __restrict__ Q,   // [2048, 512]
    const float* __restrict__ X,   // [N, 512]
    const float* __restrict__ xsq, // [N]
    float* __restrict__ candS,     // [2048, NCHUNKS, 5]
    int* __restrict__ candI,
    int N, int ntiles)
{
    __shared__ union {
        struct { float As[BK][BM + 4]; float Xs[BK][BN]; } s;  // 8.7 + 32.8 KB
        struct { float ms[BM][16 * 5]; int mi[BM][16 * 5]; } m; // 40 KB
    } sm;

    const int t = threadIdx.x;
    const int tn = t & 15;   // column group
    const int tm = t >> 4;   // row group
    const int qtile = blockIdx.x;
    const int chunk = blockIdx.y;

    float bestS[4][5];
    int bestI[4][5];
#pragma unroll
    for (int i = 0; i < 4; ++i)
#pragma unroll
        for (int r = 0; r < 5; ++r) { bestS[i][r] = FLT_MAX; bestI[i][r] = -1; }

    // A staging mapping: thread t loads 8 consecutive k's of row (t&63)
    const int am = t & 63;
    const int ak = (t >> 6) * 8;
    const float* Qrow = Q + (size_t)(qtile * BM + am) * D;

    for (int tile = chunk; tile < ntiles; tile += NCHUNKS) {
        const int n0 = tile * BN;

        // accumulator init = xsq[n] (FLT_MAX past N; those rows are zero-filled)
        float acc[4][16];
#pragma unroll
        for (int g = 0; g < 4; ++g)
#pragma unroll
            for (int jj = 0; jj < 4; ++jj) {
                int n = n0 + tn * 4 + g * 64 + jj;
                float v = (n < N) ? xsq[n] : FLT_MAX;
                acc[0][g * 4 + jj] = v;
                acc[1][g * 4 + jj] = v;
                acc[2][g * 4 + jj] = v;
                acc[3][g * 4 + jj] = v;
            }

        const int nrow = n0 + t;
        const bool nvalid = nrow < N;
        const float* Xrow = X + (size_t)nrow * D;

        for (int k0 = 0; k0 < D; k0 += BK) {
            __syncthreads();
            // stage A tile transposed, scaled by -2 (conflict-free: lanes write consecutive m)
            {
                float4 v0 = *(const float4*)(Qrow + k0 + ak);
                float4 v1 = *(const float4*)(Qrow + k0 + ak + 4);
                sm.s.As[ak + 0][am] = -2.0f * v0.x;
                sm.s.As[ak + 1][am] = -2.0f * v0.y;
                sm.s.As[ak + 2][am] = -2.0f * v0.z;
                sm.s.As[ak + 3][am] = -2.0f * v0.w;
                sm.s.As[ak + 4][am] = -2.0f * v1.x;
                sm.s.As[ak + 5][am] = -2.0f * v1.y;
                sm.s.As[ak + 6][am] = -2.0f * v1.z;
                sm.s.As[ak + 7][am] = -2.0f * v1.w;
            }
            // stage X tile transposed (lane t = point row; writes conflict-free)
            if (nvalid) {
#pragma unroll
                for (int kk = 0; kk < BK; kk += 4) {
                    float4 v = *(const float4*)(Xrow + k0 + kk);
                    sm.s.Xs[kk + 0][t] = v.x;
                    sm.s.Xs[kk + 1][t] = v.y;
                    sm.s.Xs[kk + 2][t] = v.z;
                    sm.s.Xs[kk + 3][t] = v.w;
                }
            } else {
#pragma unroll
                for (int kk = 0; kk < BK; ++kk) sm.s.Xs[kk][t] = 0.0f;
            }
            __syncthreads();

#pragma unroll 8
            for (int k = 0; k < BK; ++k) {
                float4 a = *(const float4*)&sm.s.As[k][tm * 4];
                float4 b0 = *(const float4*)&sm.s.Xs[k][tn * 4];
                float4 b1 = *(const float4*)&sm.s.Xs[k][tn * 4 + 64];
                float4 b2 = *(const float4*)&sm.s.Xs[k][tn * 4 + 128];
                float4 b3 = *(const float4*)&sm.s.Xs[k][tn * 4 + 192];
                float av[4] = {a.x, a.y, a.z, a.w};
                float bv[16] = {b0.x, b0.y, b0.z, b0.w,
                                b1.x, b1.y, b1.z, b1.w,
                                b2.x, b2.y, b2.z, b2.w,
                                b3.x, b3.y, b3.z, b3.w};
#pragma unroll
                for (int i = 0; i < 4; ++i)
#pragma unroll
                    for (int j = 0; j < 16; ++j)
                        acc[i][j] += av[i] * bv[j];
            }
        }

        // fold this tile's 64 scores/thread into running top-5 lists
#pragma unroll
        for (int i = 0; i < 4; ++i)
#pragma unroll
            for (int g = 0; g < 4; ++g)
#pragma unroll
                for (int jj = 0; jj < 4; ++jj)
                    insert5(bestS[i], bestI[i], acc[i][g * 4 + jj],
                            n0 + tn * 4 + g * 64 + jj);
    }

    // merge the 16 column-group lists per query via LDS
    __syncthreads();
#pragma unroll
    for (int i = 0; i < 4; ++i) {
        int q = tm * 4 + i;
#pragma unroll
        for (int r = 0; r < 5; ++r) {
            sm.m.ms[q][tn * 5 + r] = bestS[i][r];
            sm.m.mi[q][tn * 5 + r] = bestI[i][r];
        }
    }
    __syncthreads();
    if (t < BM) {
        float fs[5]; int fi[5];
#pragma unroll
        for (int r = 0; r < 5; ++r) { fs[r] = FLT_MAX; fi[r] = -1; }
        for (int i = 0; i < 16 * 5; ++i)
            insert5(fs, fi, sm.m.ms[t][i], sm.m.mi[t][i]);
        size_t base = ((size_t)(qtile * BM + t) * NCHUNKS + chunk) * 5;
#pragma unroll
        for (int r = 0; r < 5; ++r) { candS[base + r] = fs[r]; candI[base + r] = fi[r]; }
    }
}

// Final per-query merge of NCHUNKS*5 candidates + neighbor gather + mean.
__global__ void merge_kernel(const float* __restrict__ X,
                             const float* __restrict__ candS,
                             const int* __restrict__ candI,
                             float* __restrict__ out) {
    const int b = blockIdx.x;
    const int t = threadIdx.x;
    __shared__ int topIdx[5];
    if (t == 0) {
        float fs[5]; int fi[5];
#pragma unroll
        for (int r = 0; r < 5; ++r) { fs[r] = FLT_MAX; fi[r] = -1; }
        const float* cs = candS + (size_t)b * NCHUNKS * 5;
        const int* ci = candI + (size_t)b * NCHUNKS * 5;
        for (int i = 0; i < NCHUNKS * 5; ++i) insert5(fs, fi, cs[i], ci[i]);
#pragma unroll
        for (int r = 0; r < 5; ++r) topIdx[r] = fi[r];
    }
    __syncthreads();
    for (int d = t; d < D; d += blockDim.x) {
        float sum = 0.0f;
#pragma unroll
        for (int r = 0; r < 5; ++r) sum += X[(size_t)topIdx[r] * D + d];
        out[(size_t)b * D + d] = sum / 5.0f;
    }
}

extern "C" void kernel_launch(void* const* d_in, const int* in_sizes, int n_in,
                              void* d_out, int out_size, void* d_ws, size_t ws_size,
                              hipStream_t stream) {
    const float* x_enc = (const float*)d_in[0];  // [2048, 1, 512] fp32
    const float* X_fit = (const float*)d_in[1];  // [N, 512] fp32
    float* out = (float*)d_out;                  // [2048, 1, 512] fp32
    const int B = 2048;
    const int N = in_sizes[1] / D;               // 100000
    const int ntiles = (N + BN - 1) / BN;        // 391

    // workspace layout: xsq[N] | candS[B*NCHUNKS*5] | candI[B*NCHUNKS*5]  (~2.4 MB)
    float* xsq = (float*)d_ws;
    size_t off = ((size_t)N * sizeof(float) + 255) & ~(size_t)255;
    float* candS = (float*)((char*)d_ws + off);
    size_t candBytes = (size_t)B * NCHUNKS * 5 * sizeof(float);
    int* candI = (int*)((char*)d_ws + off + candBytes);

    hipLaunchKernelGGL(xsq_kernel, dim3((N + 3) / 4), dim3(256), 0, stream, X_fit, xsq, N);
    hipLaunchKernelGGL(score_kernel, dim3(B / BM, NCHUNKS), dim3(256), 0, stream,
                       x_enc, X_fit, xsq, candS, candI, N, ntiles);
    hipLaunchKernelGGL(merge_kernel, dim3(B), dim3(256), 0, stream, X_fit, candS, candI, out);
}

// Round 2
// 1339.859 us; speedup vs baseline: 3.0128x; 3.0128x over previous
//
#include <hip/hip_runtime.h>
#include <float.h>

#define D 512
#define BM 128
#define BN 128
#define BK 32
#define NCH 32          // chunks over the point dim (grid.y)
#define MPC 8           // approx candidates kept per (query, chunk)
#define TR 16           // candidates exactly rescored per query

typedef __attribute__((ext_vector_type(8))) short short8;
typedef __attribute__((ext_vector_type(4))) float f32x4;
typedef const __attribute__((address_space(1))) void gv_t;
typedef __attribute__((address_space(3))) void lv_t;

__device__ __forceinline__ void gl2lds16(const void* g, void* l) {
    __builtin_amdgcn_global_load_lds((gv_t*)g, (lv_t*)l, 16, 0, 0);
}

__device__ __forceinline__ unsigned short f2bf(float f) {
    unsigned u = __float_as_uint(f);
    return (unsigned short)((u + 0x7FFF + ((u >> 16) & 1)) >> 16);
}

template <int K>
__device__ __forceinline__ void insertK(float* bs, int* bi, float v, int id) {
    if (v < bs[K - 1]) {
        bs[K - 1] = v; bi[K - 1] = id;
#pragma unroll
        for (int r = K - 1; r >= 1; --r) {
            if (bs[r] < bs[r - 1]) {
                float tf = bs[r]; bs[r] = bs[r - 1]; bs[r - 1] = tf;
                int ti = bi[r]; bi[r] = bi[r - 1]; bi[r - 1] = ti;
            }
        }
    }
}

// X fp32 -> bf16 (zero-padded rows) + exact fp32 ||x||^2 (1e30 for pad rows).
// One wave per row; lane covers 8 contiguous cols.
__global__ void convert_x(const float* __restrict__ X, unsigned short* __restrict__ Xbf,
                          float* __restrict__ xsq, int N, int padN) {
    int row = blockIdx.x * 4 + (threadIdx.x >> 6);
    int lane = threadIdx.x & 63;
    if (row >= padN) return;
    unsigned short ob[8];
    float s = 0.0f;
    if (row < N) {
        const float* p = X + (size_t)row * D + lane * 8;
        float4 a = *(const float4*)p;
        float4 b = *(const float4*)(p + 4);
        s = a.x * a.x + a.y * a.y + a.z * a.z + a.w * a.w
          + b.x * b.x + b.y * b.y + b.z * b.z + b.w * b.w;
        ob[0] = f2bf(a.x); ob[1] = f2bf(a.y); ob[2] = f2bf(a.z); ob[3] = f2bf(a.w);
        ob[4] = f2bf(b.x); ob[5] = f2bf(b.y); ob[6] = f2bf(b.z); ob[7] = f2bf(b.w);
    } else {
#pragma unroll
        for (int i = 0; i < 8; ++i) ob[i] = 0;
    }
    *(uint4*)(Xbf + (size_t)row * D + lane * 8) = *(uint4*)ob;
#pragma unroll
    for (int off = 32; off > 0; off >>= 1) s += __shfl_down(s, off, 64);
    if (lane == 0) xsq[row] = (row < N) ? s : 1e30f;
}

// Q fp32 -> bf16(-2*q). One wave per row.
__global__ void convert_q(const float* __restrict__ Q, unsigned short* __restrict__ Qbf) {
    int row = blockIdx.x * 4 + (threadIdx.x >> 6);
    int lane = threadIdx.x & 63;
    const float* p = Q + (size_t)row * D + lane * 8;
    float4 a = *(const float4*)p;
    float4 b = *(const float4*)(p + 4);
    unsigned short ob[8];
    ob[0] = f2bf(-2.0f * a.x); ob[1] = f2bf(-2.0f * a.y);
    ob[2] = f2bf(-2.0f * a.z); ob[3] = f2bf(-2.0f * a.w);
    ob[4] = f2bf(-2.0f * b.x); ob[5] = f2bf(-2.0f * b.y);
    ob[6] = f2bf(-2.0f * b.z); ob[7] = f2bf(-2.0f * b.w);
    *(uint4*)(Qbf + (size_t)row * D + lane * 8) = *(uint4*)ob;
}

// MFMA coarse scorer: s(q,n) = xsq[n] + sum_k Qbf[q,k]*Xbf[n,k]  (Qbf pre-scaled by -2).
// Block = 128 queries x 128 points per tile; per (query,chunk) keep approx top-8.
__global__ __launch_bounds__(256, 2) void score_mfma(
    const unsigned short* __restrict__ Qbf,
    const unsigned short* __restrict__ Xbf,
    const float* __restrict__ xsq,
    float* __restrict__ candS, int* __restrict__ candI,
    int padTiles)
{
    __shared__ union {
        struct { unsigned short A[BM * BK]; unsigned short B[BN * BK]; } st; // 16 KB
        float sc[64 * 132];                                                  // 33.8 KB
        struct { float ms[256][MPC]; int mi[256][MPC]; } mg;                 // 16 KB
    } u;

    const int tid = threadIdx.x;
    const int wave = tid >> 6;
    const int lane = tid & 63;
    const int quad = lane >> 4;
    const int l15 = lane & 15;
    const int wm = wave & 1;   // wave's m-half (0/1)
    const int wn = wave >> 1;  // wave's n-half (0/1)
    const int qt = blockIdx.x;
    const int chunk = blockIdx.y;

    const int m_scan = tid >> 1;   // query this thread selects for
    const int h_scan = tid & 1;    // which half of n it scans

    float ts[MPC]; int ti8[MPC];
#pragma unroll
    for (int r = 0; r < MPC; ++r) { ts[r] = FLT_MAX; ti8[r] = -1; }

    // staging source mapping: iteration it, flat lane gl = it*256+tid covers
    // LDS bytes [gl*16, +16) = row gl>>2, k-segment (gl&3)*8 elements.
    const int srow = tid >> 2;
    const int skseg = (tid & 3) * 8;

    for (int tile = chunk; tile < padTiles; tile += NCH) {
        const int n0 = tile * BN;

        f32x4 acc[4][4];
#pragma unroll
        for (int tj = 0; tj < 4; ++tj) {
            float v = xsq[n0 + wn * 64 + tj * 16 + l15];
            f32x4 vv = {v, v, v, v};
#pragma unroll
            for (int ti = 0; ti < 4; ++ti) acc[ti][tj] = vv;
        }

        for (int k0 = 0; k0 < D; k0 += BK) {
            __syncthreads();
            // stage A (queries) and B (points): 2 iterations of 256 lanes x 16B each
            gl2lds16(Qbf + ((size_t)(qt * BM + srow) * D + k0 + skseg),
                     u.st.A + (size_t)(wave * 64) * 8);
            gl2lds16(Qbf + ((size_t)(qt * BM + 64 + srow) * D + k0 + skseg),
                     u.st.A + (size_t)(256 + wave * 64) * 8);
            gl2lds16(Xbf + ((size_t)(n0 + srow) * D + k0 + skseg),
                     u.st.B + (size_t)(wave * 64) * 8);
            gl2lds16(Xbf + ((size_t)(n0 + 64 + srow) * D + k0 + skseg),
                     u.st.B + (size_t)(256 + wave * 64) * 8);
            __syncthreads();

            short8 af[4], bf[4];
#pragma unroll
            for (int ti = 0; ti < 4; ++ti)
                af[ti] = *(const short8*)&u.st.A[(wm * 64 + ti * 16 + l15) * BK + quad * 8];
#pragma unroll
            for (int tj = 0; tj < 4; ++tj)
                bf[tj] = *(const short8*)&u.st.B[(wn * 64 + tj * 16 + l15) * BK + quad * 8];
#pragma unroll
            for (int ti = 0; ti < 4; ++ti)
#pragma unroll
                for (int tj = 0; tj < 4; ++tj)
                    acc[ti][tj] = __builtin_amdgcn_mfma_f32_16x16x32_bf16(
                        af[ti], bf[tj], acc[ti][tj], 0, 0, 0);
        }

        // selection: dump scores to LDS (layout sc[n_local][m], stride 132) in 2 phases
#pragma unroll
        for (int p = 0; p < 2; ++p) {
            __syncthreads();
            if (wn == p) {
#pragma unroll
                for (int ti = 0; ti < 4; ++ti)
#pragma unroll
                    for (int tj = 0; tj < 4; ++tj) {
                        int n_loc = tj * 16 + l15;
                        int mbase = wm * 64 + ti * 16 + quad * 4;
                        *(f32x4*)&u.sc[n_loc * 132 + mbase] = acc[ti][tj];
                    }
            }
            __syncthreads();
#pragma unroll 8
            for (int i = 0; i < 32; ++i) {
                int n_loc = h_scan * 32 + i;
                float s = u.sc[n_loc * 132 + m_scan];
                insertK<MPC>(ts, ti8, s, n0 + p * 64 + n_loc);
            }
        }
    }

    // merge the two half-lists per query, write per-(query,chunk) top-8
    __syncthreads();
#pragma unroll
    for (int r = 0; r < MPC; ++r) { u.mg.ms[tid][r] = ts[r]; u.mg.mi[tid][r] = ti8[r]; }
    __syncthreads();
    if (h_scan == 0) {
#pragma unroll
        for (int r = 0; r < MPC; ++r)
            insertK<MPC>(ts, ti8, u.mg.ms[tid + 1][r], u.mg.mi[tid + 1][r]);
        size_t base = ((size_t)(qt * BM + m_scan) * NCH + chunk) * MPC;
#pragma unroll
        for (int r = 0; r < MPC; ++r) { candS[base + r] = ts[r]; candI[base + r] = ti8[r]; }
    }
}

// Per query: approx top-16 of the 256 chunk candidates -> exact fp32 rescore ->
// exact top-5 -> gather + mean.
__global__ void rescore_kernel(const float* __restrict__ Q, const float* __restrict__ X,
                               const float* __restrict__ xsq,
                               const float* __restrict__ candS, const int* __restrict__ candI,
                               float* __restrict__ out) {
    const int b = blockIdx.x;
    const int tid = threadIdx.x;
    const int wave = tid >> 6;
    const int lane = tid & 63;
    __shared__ int exI[TR];
    __shared__ float exS[TR];
    __shared__ int top5[5];

    if (tid == 0) {
        float as[TR]; int ai[TR];
#pragma unroll
        for (int r = 0; r < TR; ++r) { as[r] = FLT_MAX; ai[r] = -1; }
        const float* cs = candS + (size_t)b * NCH * MPC;
        const int* ci = candI + (size_t)b * NCH * MPC;
        for (int i = 0; i < NCH * MPC; ++i) insertK<TR>(as, ai, cs[i], ci[i]);
#pragma unroll
        for (int r = 0; r < TR; ++r) exI[r] = ai[r];
    }
    __syncthreads();

    // exact fp32 rescore: wave w handles candidates 4w..4w+3
    const float* qr = Q + (size_t)b * D;
#pragma unroll
    for (int cc = 0; cc < 4; ++cc) {
        int c = wave * 4 + cc;
        int idx = exI[c];
        const float* xr = X + (size_t)idx * D;
        float4 qa = *(const float4*)(qr + lane * 8);
        float4 qb = *(const float4*)(qr + lane * 8 + 4);
        float4 xa = *(const float4*)(xr + lane * 8);
        float4 xb = *(const float4*)(xr + lane * 8 + 4);
        float p = qa.x * xa.x + qa.y * xa.y + qa.z * xa.z + qa.w * xa.w
                + qb.x * xb.x + qb.y * xb.y + qb.z * xb.z + qb.w * xb.w;
#pragma unroll
        for (int off = 32; off > 0; off >>= 1) p += __shfl_down(p, off, 64);
        if (lane == 0) exS[c] = xsq[idx] - 2.0f * p;
    }
    __syncthreads();

    if (tid == 0) {
        float fs[5]; int fi[5];
#pragma unroll
        for (int r = 0; r < 5; ++r) { fs[r] = FLT_MAX; fi[r] = -1; }
        for (int i = 0; i < TR; ++i) insertK<5>(fs, fi, exS[i], exI[i]);
#pragma unroll
        for (int r = 0; r < 5; ++r) top5[r] = fi[r];
    }
    __syncthreads();

#pragma unroll
    for (int dd = 0; dd < 2; ++dd) {
        int d = tid + dd * 256;
        float s = 0.0f;
#pragma unroll
        for (int r = 0; r < 5; ++r) s += X[(size_t)top5[r] * D + d];
        out[(size_t)b * D + d] = s / 5.0f;
    }
}

extern "C" void kernel_launch(void* const* d_in, const int* in_sizes, int n_in,
                              void* d_out, int out_size, void* d_ws, size_t ws_size,
                              hipStream_t stream) {
    const float* x_enc = (const float*)d_in[0];  // [2048, 512] fp32
    const float* X_fit = (const float*)d_in[1];  // [N, 512] fp32
    float* out = (float*)d_out;
    const int B = in_sizes[0] / D;               // 2048
    const int N = in_sizes[1] / D;               // 100000
    const int padN = ((N + BN - 1) / BN) * BN;   // 100096
    const int padTiles = padN / BN;              // 782
    const int qtiles = B / BM;                   // 16

    // ws layout (16B-aligned blocks):
    char* w = (char*)d_ws;
    unsigned short* Xbf = (unsigned short*)w;            w += (size_t)padN * D * 2;
    unsigned short* Qbf = (unsigned short*)w;            w += (size_t)B * D * 2;
    float* xsq = (float*)w;                              w += (size_t)padN * 4;
    float* candS = (float*)w;                            w += (size_t)B * NCH * MPC * 4;
    int* candI = (int*)w;

    hipLaunchKernelGGL(convert_x, dim3(padN / 4), dim3(256), 0, stream, X_fit, Xbf, xsq, N, padN);
    hipLaunchKernelGGL(convert_q, dim3(B / 4), dim3(256), 0, stream, x_enc, Qbf);
    hipLaunchKernelGGL(score_mfma, dim3(qtiles, NCH), dim3(256), 0, stream,
                       Qbf, Xbf, xsq, candS, candI, padTiles);
    hipLaunchKernelGGL(rescore_kernel, dim3(B), dim3(256), 0, stream,
                       x_enc, X_fit, xsq, candS, candI, out);
}

// Round 3
// 990.693 us; speedup vs baseline: 4.0747x; 1.3524x over previous
//
#include <hip/hip_runtime.h>
#include <float.h>

#define D 512
#define BM 128
#define BN 128
#define BK 32
#define NCH 64          // chunks over the point dim (grid.y)
#define MPC 8           // approx candidates kept per (query, chunk)
#define TR 16           // candidates exactly rescored per query
#define SCS 148         // score-dump m-stride (148 mod 32 = 20 -> conflict-free b128 dump)

typedef __attribute__((ext_vector_type(8))) short short8;
typedef __attribute__((ext_vector_type(4))) float f32x4;
typedef const __attribute__((address_space(1))) void gv_t;
typedef __attribute__((address_space(3))) void lv_t;

__device__ __forceinline__ void gl2lds16(const void* g, void* l) {
    __builtin_amdgcn_global_load_lds((gv_t*)g, (lv_t*)l, 16, 0, 0);
}

__device__ __forceinline__ unsigned short f2bf(float f) {
    unsigned u = __float_as_uint(f);
    return (unsigned short)((u + 0x7FFF + ((u >> 16) & 1)) >> 16);
}

template <int K>
__device__ __forceinline__ void insertK(float* bs, int* bi, float v, int id) {
    if (v < bs[K - 1]) {
        bs[K - 1] = v; bi[K - 1] = id;
#pragma unroll
        for (int r = K - 1; r >= 1; --r) {
            if (bs[r] < bs[r - 1]) {
                float tf = bs[r]; bs[r] = bs[r - 1]; bs[r - 1] = tf;
                int ti = bi[r]; bi[r] = bi[r - 1]; bi[r - 1] = ti;
            }
        }
    }
}

// X fp32 -> bf16 (zero-padded rows) + exact fp32 ||x||^2 (1e30 for pad rows).
__global__ void convert_x(const float* __restrict__ X, unsigned short* __restrict__ Xbf,
                          float* __restrict__ xsq, int N, int padN) {
    int row = blockIdx.x * 4 + (threadIdx.x >> 6);
    int lane = threadIdx.x & 63;
    if (row >= padN) return;
    unsigned short ob[8];
    float s = 0.0f;
    if (row < N) {
        const float* p = X + (size_t)row * D + lane * 8;
        float4 a = *(const float4*)p;
        float4 b = *(const float4*)(p + 4);
        s = a.x * a.x + a.y * a.y + a.z * a.z + a.w * a.w
          + b.x * b.x + b.y * b.y + b.z * b.z + b.w * b.w;
        ob[0] = f2bf(a.x); ob[1] = f2bf(a.y); ob[2] = f2bf(a.z); ob[3] = f2bf(a.w);
        ob[4] = f2bf(b.x); ob[5] = f2bf(b.y); ob[6] = f2bf(b.z); ob[7] = f2bf(b.w);
    } else {
#pragma unroll
        for (int i = 0; i < 8; ++i) ob[i] = 0;
    }
    *(uint4*)(Xbf + (size_t)row * D + lane * 8) = *(uint4*)ob;
#pragma unroll
    for (int off = 32; off > 0; off >>= 1) s += __shfl_down(s, off, 64);
    if (lane == 0) xsq[row] = (row < N) ? s : 1e30f;
}

// Q fp32 -> bf16(-2*q).
__global__ void convert_q(const float* __restrict__ Q, unsigned short* __restrict__ Qbf) {
    int row = blockIdx.x * 4 + (threadIdx.x >> 6);
    int lane = threadIdx.x & 63;
    const float* p = Q + (size_t)row * D + lane * 8;
    float4 a = *(const float4*)p;
    float4 b = *(const float4*)(p + 4);
    unsigned short ob[8];
    ob[0] = f2bf(-2.0f * a.x); ob[1] = f2bf(-2.0f * a.y);
    ob[2] = f2bf(-2.0f * a.z); ob[3] = f2bf(-2.0f * a.w);
    ob[4] = f2bf(-2.0f * b.x); ob[5] = f2bf(-2.0f * b.y);
    ob[6] = f2bf(-2.0f * b.z); ob[7] = f2bf(-2.0f * b.w);
    *(uint4*)(Qbf + (size_t)row * D + lane * 8) = *(uint4*)ob;
}

// MFMA coarse scorer with XOR-swizzled LDS staging (conflict-free frag reads).
__global__ __launch_bounds__(256, 2) void score_mfma(
    const unsigned short* __restrict__ Qbf,
    const unsigned short* __restrict__ Xbf,
    const float* __restrict__ xsq,
    float* __restrict__ candS, int* __restrict__ candI,
    int padTiles)
{
    __shared__ union {
        struct { unsigned short A[BM * BK]; unsigned short B[BN * BK]; } st; // 16 KB
        float sc[64 * SCS];                                                  // 37.9 KB
        struct { float ms[256][MPC]; int mi[256][MPC]; } mg;                 // 16 KB
    } u;

    const int tid = threadIdx.x;
    const int wave = tid >> 6;
    const int lane = tid & 63;
    const int quad = lane >> 4;
    const int l15 = lane & 15;
    const int wm = wave & 1;
    const int wn = wave >> 1;
    const int qt = blockIdx.x;
    const int chunk = blockIdx.y;

    const int m_scan = tid >> 1;
    const int h_scan = tid & 1;

    float ts[MPC]; int ti8[MPC];
#pragma unroll
    for (int r = 0; r < MPC; ++r) { ts[r] = FLT_MAX; ti8[r] = -1; }

    // staging: lane tid -> LDS row srow=tid>>2, LDS seg (tid&3); SOURCE k-seg is
    // XOR-swizzled by the row so frag reads are bank-conflict-free.
    const int srow = tid >> 2;
    const int sseg = (((tid & 3) ^ ((tid >> 3) & 3)) * 8);
    // frag read: k-window quad*8 of row r lives at LDS seg quad ^ ((r>>1)&3)
    const int kxor = ((quad ^ ((l15 >> 1) & 3)) * 8);

    for (int tile = chunk; tile < padTiles; tile += NCH) {
        const int n0 = tile * BN;

        f32x4 acc[4][4];
#pragma unroll
        for (int tj = 0; tj < 4; ++tj) {
            float v = xsq[n0 + wn * 64 + tj * 16 + l15];
            f32x4 vv = {v, v, v, v};
#pragma unroll
            for (int ti = 0; ti < 4; ++ti) acc[ti][tj] = vv;
        }

        for (int k0 = 0; k0 < D; k0 += BK) {
            __syncthreads();
            gl2lds16(Qbf + ((size_t)(qt * BM + srow) * D + k0 + sseg),
                     u.st.A + (size_t)(wave * 64) * 8);
            gl2lds16(Qbf + ((size_t)(qt * BM + 64 + srow) * D + k0 + sseg),
                     u.st.A + (size_t)(256 + wave * 64) * 8);
            gl2lds16(Xbf + ((size_t)(n0 + srow) * D + k0 + sseg),
                     u.st.B + (size_t)(wave * 64) * 8);
            gl2lds16(Xbf + ((size_t)(n0 + 64 + srow) * D + k0 + sseg),
                     u.st.B + (size_t)(256 + wave * 64) * 8);
            __syncthreads();

            short8 af[4], bf[4];
#pragma unroll
            for (int ti = 0; ti < 4; ++ti)
                af[ti] = *(const short8*)&u.st.A[(wm * 64 + ti * 16 + l15) * BK + kxor];
#pragma unroll
            for (int tj = 0; tj < 4; ++tj)
                bf[tj] = *(const short8*)&u.st.B[(wn * 64 + tj * 16 + l15) * BK + kxor];
#pragma unroll
            for (int ti = 0; ti < 4; ++ti)
#pragma unroll
                for (int tj = 0; tj < 4; ++tj)
                    acc[ti][tj] = __builtin_amdgcn_mfma_f32_16x16x32_bf16(
                        af[ti], bf[tj], acc[ti][tj], 0, 0, 0);
        }

        // selection: dump scores (layout sc[n_local][m] stride SCS=148) in 2 n-phases
#pragma unroll
        for (int p = 0; p < 2; ++p) {
            __syncthreads();
            if (wn == p) {
#pragma unroll
                for (int ti = 0; ti < 4; ++ti)
#pragma unroll
                    for (int tj = 0; tj < 4; ++tj)
                        *(f32x4*)&u.sc[(tj * 16 + l15) * SCS + wm * 64 + ti * 16 + quad * 4] =
                            acc[ti][tj];
            }
            __syncthreads();
#pragma unroll 8
            for (int i = 0; i < 32; ++i) {
                int n_loc = h_scan * 32 + i;
                float s = u.sc[n_loc * SCS + m_scan];
                insertK<MPC>(ts, ti8, s, n0 + p * 64 + n_loc);
            }
        }
    }

    // merge the two half-lists per query, write per-(query,chunk) top-8
    __syncthreads();
#pragma unroll
    for (int r = 0; r < MPC; ++r) { u.mg.ms[tid][r] = ts[r]; u.mg.mi[tid][r] = ti8[r]; }
    __syncthreads();
    if (h_scan == 0) {
#pragma unroll
        for (int r = 0; r < MPC; ++r)
            insertK<MPC>(ts, ti8, u.mg.ms[tid + 1][r], u.mg.mi[tid + 1][r]);
        size_t base = ((size_t)(qt * BM + m_scan) * NCH + chunk) * MPC;
#pragma unroll
        for (int r = 0; r < MPC; ++r) { candS[base + r] = ts[r]; candI[base + r] = ti8[r]; }
    }
}

// Per query: wave-parallel merge of 64 sorted chunk-lists -> approx top-16 ->
// exact fp32 rescore -> exact top-5 -> gather + mean.
__global__ void rescore_kernel(const float* __restrict__ Q, const float* __restrict__ X,
                               const float* __restrict__ xsq,
                               const float* __restrict__ candS, const int* __restrict__ candI,
                               float* __restrict__ out) {
    const int b = blockIdx.x;
    const int tid = threadIdx.x;
    const int wave = tid >> 6;
    const int lane = tid & 63;
    __shared__ int exI[TR];
    __shared__ float exS[TR];
    __shared__ int top5[5];

    if (wave == 0) {
        // lane l owns chunk l's sorted 8-list; 16 rounds of wave-argmin
        const float* cs = candS + (size_t)b * NCH * MPC;
        const int* ci = candI + (size_t)b * NCH * MPC;
        int h = 0;
        float cur = cs[lane * MPC];
        for (int r = 0; r < TR; ++r) {
            float v = cur; int wl = lane;
#pragma unroll
            for (int off = 1; off < 64; off <<= 1) {
                float ov = __shfl_xor(v, off, 64);
                int owl = __shfl_xor(wl, off, 64);
                if (ov < v || (ov == v && owl < wl)) { v = ov; wl = owl; }
            }
            if (lane == wl) {
                exI[r] = ci[lane * MPC + h];
                ++h;
                cur = (h < MPC) ? cs[lane * MPC + h] : FLT_MAX;
            }
        }
    }
    __syncthreads();

    // exact fp32 rescore: wave w handles candidates 4w..4w+3
    const float* qr = Q + (size_t)b * D;
#pragma unroll
    for (int cc = 0; cc < 4; ++cc) {
        int c = wave * 4 + cc;
        int idx = exI[c];
        const float* xr = X + (size_t)idx * D;
        float4 qa = *(const float4*)(qr + lane * 8);
        float4 qb = *(const float4*)(qr + lane * 8 + 4);
        float4 xa = *(const float4*)(xr + lane * 8);
        float4 xb = *(const float4*)(xr + lane * 8 + 4);
        float p = qa.x * xa.x + qa.y * xa.y + qa.z * xa.z + qa.w * xa.w
                + qb.x * xb.x + qb.y * xb.y + qb.z * xb.z + qb.w * xb.w;
#pragma unroll
        for (int off = 32; off > 0; off >>= 1) p += __shfl_down(p, off, 64);
        if (lane == 0) exS[c] = xsq[idx] - 2.0f * p;
    }
    __syncthreads();

    if (tid == 0) {
        float fs[5]; int fi[5];
#pragma unroll
        for (int r = 0; r < 5; ++r) { fs[r] = FLT_MAX; fi[r] = -1; }
        for (int i = 0; i < TR; ++i) insertK<5>(fs, fi, exS[i], exI[i]);
#pragma unroll
        for (int r = 0; r < 5; ++r) top5[r] = fi[r];
    }
    __syncthreads();

#pragma unroll
    for (int dd = 0; dd < 2; ++dd) {
        int d = tid + dd * 256;
        float s = 0.0f;
#pragma unroll
        for (int r = 0; r < 5; ++r) s += X[(size_t)top5[r] * D + d];
        out[(size_t)b * D + d] = s / 5.0f;
    }
}

extern "C" void kernel_launch(void* const* d_in, const int* in_sizes, int n_in,
                              void* d_out, int out_size, void* d_ws, size_t ws_size,
                              hipStream_t stream) {
    const float* x_enc = (const float*)d_in[0];
    const float* X_fit = (const float*)d_in[1];
    float* out = (float*)d_out;
    const int B = in_sizes[0] / D;               // 2048
    const int N = in_sizes[1] / D;               // 100000
    const int padN = ((N + BN - 1) / BN) * BN;   // 100096
    const int padTiles = padN / BN;              // 782
    const int qtiles = B / BM;                   // 16

    char* w = (char*)d_ws;
    unsigned short* Xbf = (unsigned short*)w;            w += (size_t)padN * D * 2;
    unsigned short* Qbf = (unsigned short*)w;            w += (size_t)B * D * 2;
    float* xsq = (float*)w;                              w += (size_t)padN * 4;
    float* candS = (float*)w;                            w += (size_t)B * NCH * MPC * 4;
    int* candI = (int*)w;

    hipLaunchKernelGGL(convert_x, dim3(padN / 4), dim3(256), 0, stream, X_fit, Xbf, xsq, N, padN);
    hipLaunchKernelGGL(convert_q, dim3(B / 4), dim3(256), 0, stream, x_enc, Qbf);
    hipLaunchKernelGGL(score_mfma, dim3(qtiles, NCH), dim3(256), 0, stream,
                       Qbf, Xbf, xsq, candS, candI, padTiles);
    hipLaunchKernelGGL(rescore_kernel, dim3(B), dim3(256), 0, stream,
                       x_enc, X_fit, xsq, candS, candI, out);
}

// Round 4
// 893.857 us; speedup vs baseline: 4.5161x; 1.1083x over previous
//
#include <hip/hip_runtime.h>
#include <float.h>

#define D 512
#define BM 128
#define BN 256
#define BK 32
#define NCH 64          // chunks over the point dim (grid.y)
#define MPC 8           // approx candidates kept per (query, chunk)
#define TR 16           // candidates exactly rescored per query
#define SCS 148         // score-dump m-stride (mod 32 = 20 -> conflict-free)

typedef __attribute__((ext_vector_type(8))) short short8;
typedef __attribute__((ext_vector_type(4))) float f32x4;
typedef const __attribute__((address_space(1))) void gv_t;
typedef __attribute__((address_space(3))) void lv_t;

__device__ __forceinline__ void gl2lds16(const void* g, void* l) {
    __builtin_amdgcn_global_load_lds((gv_t*)g, (lv_t*)l, 16, 0, 0);
}

__device__ __forceinline__ unsigned short f2bf(float f) {
    unsigned u = __float_as_uint(f);
    return (unsigned short)((u + 0x7FFF + ((u >> 16) & 1)) >> 16);
}

template <int K>
__device__ __forceinline__ void insertK(float* bs, int* bi, float v, int id) {
    if (v < bs[K - 1]) {
        bs[K - 1] = v; bi[K - 1] = id;
#pragma unroll
        for (int r = K - 1; r >= 1; --r) {
            if (bs[r] < bs[r - 1]) {
                float tf = bs[r]; bs[r] = bs[r - 1]; bs[r - 1] = tf;
                int ti = bi[r]; bi[r] = bi[r - 1]; bi[r - 1] = ti;
            }
        }
    }
}

// X fp32 -> bf16 (zero-padded rows) + exact fp32 ||x||^2 (1e30 for pad rows).
__global__ void convert_x(const float* __restrict__ X, unsigned short* __restrict__ Xbf,
                          float* __restrict__ xsq, int N, int padN) {
    int row = blockIdx.x * 4 + (threadIdx.x >> 6);
    int lane = threadIdx.x & 63;
    if (row >= padN) return;
    unsigned short ob[8];
    float s = 0.0f;
    if (row < N) {
        const float* p = X + (size_t)row * D + lane * 8;
        float4 a = *(const float4*)p;
        float4 b = *(const float4*)(p + 4);
        s = a.x * a.x + a.y * a.y + a.z * a.z + a.w * a.w
          + b.x * b.x + b.y * b.y + b.z * b.z + b.w * b.w;
        ob[0] = f2bf(a.x); ob[1] = f2bf(a.y); ob[2] = f2bf(a.z); ob[3] = f2bf(a.w);
        ob[4] = f2bf(b.x); ob[5] = f2bf(b.y); ob[6] = f2bf(b.z); ob[7] = f2bf(b.w);
    } else {
#pragma unroll
        for (int i = 0; i < 8; ++i) ob[i] = 0;
    }
    *(uint4*)(Xbf + (size_t)row * D + lane * 8) = *(uint4*)ob;
#pragma unroll
    for (int off = 32; off > 0; off >>= 1) s += __shfl_down(s, off, 64);
    if (lane == 0) xsq[row] = (row < N) ? s : 1e30f;
}

// Q fp32 -> bf16(-2*q).
__global__ void convert_q(const float* __restrict__ Q, unsigned short* __restrict__ Qbf) {
    int row = blockIdx.x * 4 + (threadIdx.x >> 6);
    int lane = threadIdx.x & 63;
    const float* p = Q + (size_t)row * D + lane * 8;
    float4 a = *(const float4*)p;
    float4 b = *(const float4*)(p + 4);
    unsigned short ob[8];
    ob[0] = f2bf(-2.0f * a.x); ob[1] = f2bf(-2.0f * a.y);
    ob[2] = f2bf(-2.0f * a.z); ob[3] = f2bf(-2.0f * a.w);
    ob[4] = f2bf(-2.0f * b.x); ob[5] = f2bf(-2.0f * b.y);
    ob[6] = f2bf(-2.0f * b.z); ob[7] = f2bf(-2.0f * b.w);
    *(uint4*)(Qbf + (size_t)row * D + lane * 8) = *(uint4*)ob;
}

// MFMA coarse scorer: 128(q) x 256(n) tile, per-wave 64x128 (4x8 frags).
__global__ __launch_bounds__(256, 2) void score_mfma(
    const unsigned short* __restrict__ Qbf,
    const unsigned short* __restrict__ Xbf,
    const float* __restrict__ xsq,
    float* __restrict__ candS, int* __restrict__ candI,
    int ntiles)
{
    __shared__ union {
        struct { unsigned short A[BM * BK]; unsigned short B[BN * BK]; } st; // 24 KB
        float sc[64 * SCS];                                                  // 37.9 KB
        struct { float ms[256][MPC]; int mi[256][MPC]; } mg;                 // 16 KB
    } u;

    const int tid = threadIdx.x;
    const int wave = tid >> 6;
    const int lane = tid & 63;
    const int quad = lane >> 4;
    const int l15 = lane & 15;
    const int wm = wave & 1;   // m-half (64 rows)
    const int wn = wave >> 1;  // n-half (128 cols)
    const int qt = blockIdx.x;
    const int chunk = blockIdx.y;

    const int m_scan = tid >> 1;
    const int h_scan = tid & 1;

    float ts[MPC]; int ti8[MPC];
#pragma unroll
    for (int r = 0; r < MPC; ++r) { ts[r] = FLT_MAX; ti8[r] = -1; }

    // staging: lane -> LDS row (tid>>2), seg (tid&3); source k-seg XOR-swizzled
    // by row so frag reads are spread across banks.
    const int srow = tid >> 2;
    const int sseg = (((tid & 3) ^ ((tid >> 3) & 3)) * 8);
    // frag read: k-window quad*8 of row r lives at seg quad ^ ((r>>1)&3)
    const int kxor = ((quad ^ ((l15 >> 1) & 3)) * 8);

    for (int tile = chunk; tile < ntiles; tile += NCH) {
        const int n0 = tile * BN;

        f32x4 acc[4][8];
#pragma unroll
        for (int tj = 0; tj < 8; ++tj) {
            float v = xsq[n0 + wn * 128 + tj * 16 + l15];
            f32x4 vv = {v, v, v, v};
#pragma unroll
            for (int ti = 0; ti < 4; ++ti) acc[ti][tj] = vv;
        }

        for (int k0 = 0; k0 < D; k0 += BK) {
            __syncthreads();
            // A: 128 rows x 32 k = 2 calls; B: 256 rows = 4 calls
            gl2lds16(Qbf + ((size_t)(qt * BM + srow) * D + k0 + sseg),
                     u.st.A + (size_t)(wave * 64) * 8);
            gl2lds16(Qbf + ((size_t)(qt * BM + 64 + srow) * D + k0 + sseg),
                     u.st.A + (size_t)(256 + wave * 64) * 8);
#pragma unroll
            for (int c = 0; c < 4; ++c)
                gl2lds16(Xbf + ((size_t)(n0 + c * 64 + srow) * D + k0 + sseg),
                         u.st.B + (size_t)(c * 256 + wave * 64) * 8);
            __syncthreads();

            short8 af[4], bf[8];
#pragma unroll
            for (int ti = 0; ti < 4; ++ti)
                af[ti] = *(const short8*)&u.st.A[(wm * 64 + ti * 16 + l15) * BK + kxor];
#pragma unroll
            for (int tj = 0; tj < 8; ++tj)
                bf[tj] = *(const short8*)&u.st.B[(wn * 128 + tj * 16 + l15) * BK + kxor];
#pragma unroll
            for (int ti = 0; ti < 4; ++ti)
#pragma unroll
                for (int tj = 0; tj < 8; ++tj)
                    acc[ti][tj] = __builtin_amdgcn_mfma_f32_16x16x32_bf16(
                        af[ti], bf[tj], acc[ti][tj], 0, 0, 0);
        }

        // selection: 4 phases over 64-col groups g; dump (layout sc[n][m], stride SCS)
#pragma unroll
        for (int g = 0; g < 4; ++g) {
            __syncthreads();
            if (wn == (g >> 1)) {
#pragma unroll
                for (int ti = 0; ti < 4; ++ti)
#pragma unroll
                    for (int jj = 0; jj < 4; ++jj)
                        *(f32x4*)&u.sc[(jj * 16 + l15) * SCS + wm * 64 + ti * 16 + quad * 4] =
                            acc[ti][(g & 1) * 4 + jj];
            }
            __syncthreads();
#pragma unroll 8
            for (int i = 0; i < 32; ++i) {
                int n_loc = h_scan * 32 + i;
                float s = u.sc[n_loc * SCS + m_scan];
                insertK<MPC>(ts, ti8, s, n0 + g * 64 + n_loc);
            }
        }
    }

    // merge the two half-lists per query, write per-(query,chunk) top-8
    __syncthreads();
#pragma unroll
    for (int r = 0; r < MPC; ++r) { u.mg.ms[tid][r] = ts[r]; u.mg.mi[tid][r] = ti8[r]; }
    __syncthreads();
    if (h_scan == 0) {
#pragma unroll
        for (int r = 0; r < MPC; ++r)
            insertK<MPC>(ts, ti8, u.mg.ms[tid + 1][r], u.mg.mi[tid + 1][r]);
        size_t base = ((size_t)(qt * BM + m_scan) * NCH + chunk) * MPC;
#pragma unroll
        for (int r = 0; r < MPC; ++r) { candS[base + r] = ts[r]; candI[base + r] = ti8[r]; }
    }
}

// Per query: wave-parallel merge of 64 sorted chunk-lists -> approx top-16 ->
// exact fp32 rescore -> exact top-5 -> gather + mean.
__global__ void rescore_kernel(const float* __restrict__ Q, const float* __restrict__ X,
                               const float* __restrict__ xsq,
                               const float* __restrict__ candS, const int* __restrict__ candI,
                               float* __restrict__ out) {
    const int b = blockIdx.x;
    const int tid = threadIdx.x;
    const int wave = tid >> 6;
    const int lane = tid & 63;
    __shared__ int exI[TR];
    __shared__ float exS[TR];
    __shared__ int top5[5];

    if (wave == 0) {
        const float* cs = candS + (size_t)b * NCH * MPC;
        const int* ci = candI + (size_t)b * NCH * MPC;
        int h = 0;
        float cur = cs[lane * MPC];
        for (int r = 0; r < TR; ++r) {
            float v = cur; int wl = lane;
#pragma unroll
            for (int off = 1; off < 64; off <<= 1) {
                float ov = __shfl_xor(v, off, 64);
                int owl = __shfl_xor(wl, off, 64);
                if (ov < v || (ov == v && owl < wl)) { v = ov; wl = owl; }
            }
            if (lane == wl) {
                exI[r] = ci[lane * MPC + h];
                ++h;
                cur = (h < MPC) ? cs[lane * MPC + h] : FLT_MAX;
            }
        }
    }
    __syncthreads();

    const float* qr = Q + (size_t)b * D;
#pragma unroll
    for (int cc = 0; cc < 4; ++cc) {
        int c = wave * 4 + cc;
        int idx = exI[c];
        const float* xr = X + (size_t)idx * D;
        float4 qa = *(const float4*)(qr + lane * 8);
        float4 qb = *(const float4*)(qr + lane * 8 + 4);
        float4 xa = *(const float4*)(xr + lane * 8);
        float4 xb = *(const float4*)(xr + lane * 8 + 4);
        float p = qa.x * xa.x + qa.y * xa.y + qa.z * xa.z + qa.w * xa.w
                + qb.x * xb.x + qb.y * xb.y + qb.z * xb.z + qb.w * xb.w;
#pragma unroll
        for (int off = 32; off > 0; off >>= 1) p += __shfl_down(p, off, 64);
        if (lane == 0) exS[c] = xsq[idx] - 2.0f * p;
    }
    __syncthreads();

    if (tid == 0) {
        float fs[5]; int fi[5];
#pragma unroll
        for (int r = 0; r < 5; ++r) { fs[r] = FLT_MAX; fi[r] = -1; }
        for (int i = 0; i < TR; ++i) insertK<5>(fs, fi, exS[i], exI[i]);
#pragma unroll
        for (int r = 0; r < 5; ++r) top5[r] = fi[r];
    }
    __syncthreads();

#pragma unroll
    for (int dd = 0; dd < 2; ++dd) {
        int d = tid + dd * 256;
        float s = 0.0f;
#pragma unroll
        for (int r = 0; r < 5; ++r) s += X[(size_t)top5[r] * D + d];
        out[(size_t)b * D + d] = s / 5.0f;
    }
}

extern "C" void kernel_launch(void* const* d_in, const int* in_sizes, int n_in,
                              void* d_out, int out_size, void* d_ws, size_t ws_size,
                              hipStream_t stream) {
    const float* x_enc = (const float*)d_in[0];
    const float* X_fit = (const float*)d_in[1];
    float* out = (float*)d_out;
    const int B = in_sizes[0] / D;               // 2048
    const int N = in_sizes[1] / D;               // 100000
    const int padN = ((N + BN - 1) / BN) * BN;   // 100096
    const int ntiles = padN / BN;                // 391
    const int qtiles = B / BM;                   // 16

    char* w = (char*)d_ws;
    unsigned short* Xbf = (unsigned short*)w;            w += (size_t)padN * D * 2;
    unsigned short* Qbf = (unsigned short*)w;            w += (size_t)B * D * 2;
    float* xsq = (float*)w;                              w += (size_t)padN * 4;
    float* candS = (float*)w;                            w += (size_t)B * NCH * MPC * 4;
    int* candI = (int*)w;

    hipLaunchKernelGGL(convert_x, dim3(padN / 4), dim3(256), 0, stream, X_fit, Xbf, xsq, N, padN);
    hipLaunchKernelGGL(convert_q, dim3(B / 4), dim3(256), 0, stream, x_enc, Qbf);
    hipLaunchKernelGGL(score_mfma, dim3(qtiles, NCH), dim3(256), 0, stream,
                       Qbf, Xbf, xsq, candS, candI, ntiles);
    hipLaunchKernelGGL(rescore_kernel, dim3(B), dim3(256), 0, stream,
                       x_enc, X_fit, xsq, candS, candI, out);
}